// Round 15
// baseline (105.756 us; speedup 1.0000x reference)
//
#include <hip/hip_runtime.h>
#include <math.h>

#define BB 4
#define NN 2048
#define CIN 64
#define HID 128
#define HEADS 4
#define NQ 16
#define KTOT (NN*HID) // 262144
#define LOG2E 1.44269504088896340736f
#define NEGBIG_BITS 0xC2C80000u   // -100.0f
#define NSL 4         // j-slices (512 j each)

typedef __attribute__((ext_vector_type(8))) _Float16 half8;
typedef __attribute__((ext_vector_type(4))) float f32x4;
typedef __attribute__((ext_vector_type(4))) unsigned uint4v;

// ---------------- k_hidden: h = x@W_in + b (f16 out), alphas (pre-scaled log2e) ----------
__global__ __launch_bounds__(256) void k_hidden(
    const float* __restrict__ x, const float* __restrict__ W_in,
    const float* __restrict__ b_in, const float* __restrict__ att_src,
    const float* __restrict__ att_dst, _Float16* __restrict__ hH,
    float* __restrict__ srcA, float* __restrict__ dstA)
{
    __shared__ float Wl[CIN * HID];   // 32 KB
    __shared__ float xl[16][CIN];     // 4 KB
    const int t = threadIdx.x;
    const int jj0 = blockIdx.x * 16;

    {
        const float4* Ws = (const float4*)W_in;
        float4* Wd = (float4*)Wl;
#pragma unroll
        for (int u = 0; u < 8; ++u) Wd[t + 256 * u] = Ws[t + 256 * u];
        ((float4*)&xl[0][0])[t] = ((const float4*)(x + (size_t)jj0 * CIN))[t];
    }
    __syncthreads();

    const int c = t & 127, rg = t >> 7;
    const int b = jj0 >> 11, j0 = (jj0 & (NN - 1)) + rg * 8;
    const int h = c >> 5;

    float acc[8];
    const float bc = b_in[c];
#pragma unroll
    for (int rr = 0; rr < 8; ++rr) acc[rr] = bc;

#pragma unroll
    for (int k4 = 0; k4 < CIN; k4 += 4) {
        const float w0 = Wl[(k4 + 0) * HID + c];
        const float w1 = Wl[(k4 + 1) * HID + c];
        const float w2 = Wl[(k4 + 2) * HID + c];
        const float w3 = Wl[(k4 + 3) * HID + c];
#pragma unroll
        for (int rr = 0; rr < 8; ++rr) {
            const float4 xv = *(const float4*)&xl[rg * 8 + rr][k4];
            acc[rr] = fmaf(xv.w, w3, fmaf(xv.z, w2, fmaf(xv.y, w1, fmaf(xv.x, w0, acc[rr]))));
        }
    }

    half8 hv;
#pragma unroll
    for (int rr = 0; rr < 8; ++rr) hv[rr] = (_Float16)acc[rr];
    *(half8*)(hH + (size_t)(b * HID + c) * NN + j0) = hv;

    const float as = att_src[c], ad = att_dst[c];
#pragma unroll
    for (int rr = 0; rr < 8; ++rr) {
        float vs = acc[rr] * as, vd = acc[rr] * ad;
#pragma unroll
        for (int m = 16; m >= 1; m >>= 1) {
            vs += __shfl_xor(vs, m, 64);
            vd += __shfl_xor(vd, m, 64);
        }
        if ((t & 31) == 0) {
            srcA[(size_t)(b * HEADS + h) * NN + j0 + rr] = vs * LOG2E;
            dstA[(size_t)(b * HEADS + h) * NN + j0 + rr] = vd * LOG2E;
        }
    }
}

// ---------------- k_adjb: adj -> bitmask (zero LDS); block 0 inits out -------------------
__global__ __launch_bounds__(256) void k_adjb(const int* __restrict__ adj,
                                              unsigned* __restrict__ adjb,
                                              const float* __restrict__ b_out,
                                              float* __restrict__ dout)
{
    const int t = threadIdx.x;
    if (blockIdx.x == 0 && t < 64) dout[t] = b_out[t & 15];
    const int gid = blockIdx.x * 256 + t;              // 0 .. N*N/8-1
    const int lane = t & 63;
    const int4* p = (const int4*)(adj + (size_t)gid * 8);
    const int4 a = p[0], b = p[1];
    unsigned byte =
        (a.x != 0 ? 1u : 0u)  | (a.y != 0 ? 2u : 0u)  | (a.z != 0 ? 4u : 0u)  | (a.w != 0 ? 8u : 0u) |
        (b.x != 0 ? 16u : 0u) | (b.y != 0 ? 32u : 0u) | (b.z != 0 ? 64u : 0u) | (b.w != 0 ? 128u : 0u);
    unsigned u = byte | (((unsigned)__shfl_xor((int)byte, 1, 64)) << 8);
    u = u | (((unsigned)__shfl_xor((int)u, 2, 64)) << 16);
    if ((lane & 3) == 0) adjb[gid >> 2] = u;
}

// ---------------- k_attn: max-occupancy register flash-GAT (no LDS) ---------------------
// grid 2048 x 256 thr; block = (iq 128, b 4, jq 4); 4 waves = 4 heads.
// Wave: 16-row i-tile x 512 j; 16 iters of {1 adj word + 2 half8 + 2 float4 loads,
// MAKEAF, 3 MFMA}. 8 waves/SIMD (launch_bounds cap 64 VGPR) hides L2 latency via TLP.
__global__ __launch_bounds__(256, 8) void k_attn(
    const unsigned* __restrict__ adjb, const _Float16* __restrict__ hH,
    const float* __restrict__ srcA, const float* __restrict__ dstA,
    float* __restrict__ P, float* __restrict__ S)
{
    const int t = threadIdx.x;
    const int lane = t & 63;
    const int h = t >> 6;                // wave id = head
    const int bx = blockIdx.x;
    const int iq = bx & 127;
    const int b = (bx >> 7) & 3;
    const int jq = bx >> 9;
    const int i0 = iq * 16;
    const int jbase = jq * 512;

    const int r16 = lane & 15;
    const int g = lane >> 4;

    const float srci = srcA[(size_t)(b * HEADS + h) * NN + i0 + r16];
    const unsigned* adjr = adjb + (size_t)(i0 + r16) * (NN / 32) + (jbase >> 5);
    const _Float16* bbase0 = hH + ((size_t)(b * HID) + h * 32 + r16) * NN + jbase + 8 * g;
    const _Float16* bbase1 = bbase0 + (size_t)16 * NN;
    const float4* dst4 = (const float4*)(dstA + (size_t)(b * HEADS + h) * NN + jbase) + 2 * g;

    f32x4 acc0 = {0.f, 0.f, 0.f, 0.f};
    f32x4 acc1 = {0.f, 0.f, 0.f, 0.f};
    f32x4 accS = {0.f, 0.f, 0.f, 0.f};
    const half8 ones = {(_Float16)1.f, (_Float16)1.f, (_Float16)1.f, (_Float16)1.f,
                        (_Float16)1.f, (_Float16)1.f, (_Float16)1.f, (_Float16)1.f};

#pragma unroll 1
    for (int n = 0; n < 16; ++n) {
        const unsigned word = adjr[n];
        const half8 bb0 = *(const half8*)(bbase0 + n * 32);
        const half8 bb1 = *(const half8*)(bbase1 + n * 32);
        const float4 dv0 = dst4[n * 8];
        const float4 dv1 = dst4[n * 8 + 1];

        const unsigned bits = word >> (8 * g);
        const float dvv[8] = {dv0.x, dv0.y, dv0.z, dv0.w, dv1.x, dv1.y, dv1.z, dv1.w};
        float wv[8];
#pragma unroll
        for (int e = 0; e < 8; ++e) {
            float s = srci + dvv[e];
            s = fmaxf(s, 0.2f * s);                                   // leaky relu (log2-scaled)
            const unsigned m = (unsigned)(((int)(bits << (31 - e))) >> 31);
            const unsigned su = __builtin_bit_cast(unsigned, s);
            wv[e] = __builtin_amdgcn_exp2f(
                __builtin_bit_cast(float, (su & m) | (NEGBIG_BITS & ~m)));
        }
        uint4v uu;
        uu[0] = __builtin_bit_cast(unsigned, __builtin_amdgcn_cvt_pkrtz(wv[0], wv[1]));
        uu[1] = __builtin_bit_cast(unsigned, __builtin_amdgcn_cvt_pkrtz(wv[2], wv[3]));
        uu[2] = __builtin_bit_cast(unsigned, __builtin_amdgcn_cvt_pkrtz(wv[4], wv[5]));
        uu[3] = __builtin_bit_cast(unsigned, __builtin_amdgcn_cvt_pkrtz(wv[6], wv[7]));
        const half8 af = __builtin_bit_cast(half8, uu);
        acc0 = __builtin_amdgcn_mfma_f32_16x16x32_f16(af, bb0, acc0, 0, 0, 0);
        acc1 = __builtin_amdgcn_mfma_f32_16x16x32_f16(af, bb1, acc1, 0, 0, 0);
        accS = __builtin_amdgcn_mfma_f32_16x16x32_f16(af, ones, accS, 0, 0, 0);
    }

    // direct store of this wave's disjoint output rows (verified layout: i=4g+r, d=r16)
    const size_t prow0 = (size_t)(jq * BB + b) * NN + i0;
#pragma unroll
    for (int r = 0; r < 4; ++r) {
        const size_t row = prow0 + 4 * g + r;
        P[row * HID + h * 32 + r16]      = acc0[r];
        P[row * HID + h * 32 + 16 + r16] = acc1[r];
        if (r16 == 0) S[row * HEADS + h] = accS[r];
    }
}

// ---------------- k_proj: combine 4 f32 partials + projection (W^T in LDS) --------------
__global__ __launch_bounds__(256) void k_proj(
    const float* __restrict__ P, const float* __restrict__ S,
    const float* __restrict__ W_out, float* __restrict__ dout)
{
    __shared__ float wlT[NQ][260];     // 16.6 KB
    __shared__ float red[256];

    const int t = threadIdx.x;
    const int k0 = blockIdx.x * 256;

#pragma unroll
    for (int u = 0; u < 4; ++u) {
        const int flat = (u * 256 + t) * 4;
        const float4 wv = *(const float4*)(W_out + (size_t)k0 * NQ + flat);
        const int krel = flat >> 4;
        const int q0 = flat & 15;
        wlT[q0 + 0][krel] = wv.x;
        wlT[q0 + 1][krel] = wv.y;
        wlT[q0 + 2][krel] = wv.z;
        wlT[q0 + 3][krel] = wv.w;
    }
    __syncthreads();

    const int q = t & 15;
    const int b = (t >> 4) & 3;
    const int ks = (t >> 6) * 64;
    const int i = (k0 + ks) >> 7;

    const float* p0 = P + (size_t)(0 * BB + b) * KTOT + k0 + ks;
    const float* p1 = P + (size_t)(1 * BB + b) * KTOT + k0 + ks;
    const float* p2 = P + (size_t)(2 * BB + b) * KTOT + k0 + ks;
    const float* p3 = P + (size_t)(3 * BB + b) * KTOT + k0 + ks;

    float acc = 0.f;
#pragma unroll
    for (int seg = 0; seg < 2; ++seg) {
        const int h = ((k0 + ks + seg * 32) >> 5) & 3;
        float rs = 0.f;
#pragma unroll
        for (int s = 0; s < NSL; ++s)
            rs += S[((size_t)(s * BB + b) * NN + i) * HEADS + h];
        const float inv = __builtin_amdgcn_rcpf(rs);
#pragma unroll
        for (int k4 = 0; k4 < 8; ++k4) {
            const int kk = seg * 32 + k4 * 4;
            const float4 a0 = *(const float4*)(p0 + kk);
            const float4 a1 = *(const float4*)(p1 + kk);
            const float4 a2 = *(const float4*)(p2 + kk);
            const float4 a3 = *(const float4*)(p3 + kk);
            const float4 wq = *(const float4*)&wlT[q][ks + kk];
            acc = fmaf(((a0.x + a1.x) + (a2.x + a3.x)) * inv, wq.x, acc);
            acc = fmaf(((a0.y + a1.y) + (a2.y + a3.y)) * inv, wq.y, acc);
            acc = fmaf(((a0.z + a1.z) + (a2.z + a3.z)) * inv, wq.z, acc);
            acc = fmaf(((a0.w + a1.w) + (a2.w + a3.w)) * inv, wq.w, acc);
        }
    }

    red[t] = acc;
    __syncthreads();
    if (t < 64)
        atomicAdd(&dout[t], red[t] + red[t + 64] + red[t + 128] + red[t + 192]);
}

extern "C" void kernel_launch(void* const* d_in, const int* in_sizes, int n_in,
                              void* d_out, int out_size, void* d_ws, size_t ws_size,
                              hipStream_t stream)
{
    const float* x       = (const float*)d_in[0];
    const int*   adj     = (const int*)d_in[1];
    const float* W_in    = (const float*)d_in[2];
    const float* b_in    = (const float*)d_in[3];
    const float* att_src = (const float*)d_in[4];
    const float* att_dst = (const float*)d_in[5];
    const float* W_out   = (const float*)d_in[6];
    const float* b_out   = (const float*)d_in[7];
    float* out = (float*)d_out;

    float* P    = (float*)d_ws;                              // NSL*BB*KTOT f32 = 16.8 MB
    float* S    = P + (size_t)NSL * BB * KTOT;               // 512 KB
    float* srcA = S + (size_t)NSL * BB * NN * HEADS;         // 128 KB
    float* dstA = srcA + (size_t)BB * HEADS * NN;            // 128 KB
    _Float16* hH = (_Float16*)(dstA + (size_t)BB * HEADS * NN);           // 2 MB
    unsigned* adjbw = (unsigned*)((char*)hH + sizeof(_Float16) * (size_t)BB * KTOT); // 512 KB

    k_hidden<<<BB * NN / 16, 256, 0, stream>>>(x, W_in, b_in, att_src, att_dst, hH, srcA, dstA);
    k_adjb<<<NN * NN / 8 / 256, 256, 0, stream>>>(adj, adjbw, b_out, out);
    // block = (iq 128, b 4, jq 4) -> 2048 blocks x 4 waves = 8192 waves = 8/SIMD
    k_attn<<<NSL * BB * (NN / 16), 256, 0, stream>>>(adjbw, hH, srcA, dstA, P, S);
    k_proj<<<KTOT / 256, 256, 0, stream>>>(P, S, W_out, out);
}

// Round 16
// 79.660 us; speedup vs baseline: 1.3276x; 1.3276x over previous
//
#include <hip/hip_runtime.h>
#include <math.h>

#define BB 4
#define NN 2048
#define CIN 64
#define HID 128
#define HEADS 4
#define NQ 16
#define KTOT (NN*HID) // 262144
#define LOG2E 1.44269504088896340736f
#define NEGBIG_BITS 0xC2C80000u   // -100.0f
#define NSL 4         // j-slices (512 j each)

typedef __attribute__((ext_vector_type(8))) _Float16 half8;
typedef __attribute__((ext_vector_type(4))) float f32x4;
typedef __attribute__((ext_vector_type(4))) unsigned uint4v;

// ---------------- k_hidden: h = x@W_in + b -> TILED hHT[b][jblk][d][j32], alphas ---------
__global__ __launch_bounds__(256) void k_hidden(
    const float* __restrict__ x, const float* __restrict__ W_in,
    const float* __restrict__ b_in, const float* __restrict__ att_src,
    const float* __restrict__ att_dst, _Float16* __restrict__ hHT,
    float* __restrict__ srcA, float* __restrict__ dstA)
{
    __shared__ float Wl[CIN * HID];   // 32 KB
    __shared__ float xl[16][CIN];     // 4 KB
    const int t = threadIdx.x;
    const int jj0 = blockIdx.x * 16;

    {
        const float4* Ws = (const float4*)W_in;
        float4* Wd = (float4*)Wl;
#pragma unroll
        for (int u = 0; u < 8; ++u) Wd[t + 256 * u] = Ws[t + 256 * u];
        ((float4*)&xl[0][0])[t] = ((const float4*)(x + (size_t)jj0 * CIN))[t];
    }
    __syncthreads();

    const int c = t & 127, rg = t >> 7;
    const int b = jj0 >> 11, j0 = (jj0 & (NN - 1)) + rg * 8;
    const int h = c >> 5;

    float acc[8];
    const float bc = b_in[c];
#pragma unroll
    for (int rr = 0; rr < 8; ++rr) acc[rr] = bc;

#pragma unroll
    for (int k4 = 0; k4 < CIN; k4 += 4) {
        const float w0 = Wl[(k4 + 0) * HID + c];
        const float w1 = Wl[(k4 + 1) * HID + c];
        const float w2 = Wl[(k4 + 2) * HID + c];
        const float w3 = Wl[(k4 + 3) * HID + c];
#pragma unroll
        for (int rr = 0; rr < 8; ++rr) {
            const float4 xv = *(const float4*)&xl[rg * 8 + rr][k4];
            acc[rr] = fmaf(xv.w, w3, fmaf(xv.z, w2, fmaf(xv.y, w1, fmaf(xv.x, w0, acc[rr]))));
        }
    }

    half8 hv;
#pragma unroll
    for (int rr = 0; rr < 8; ++rr) hv[rr] = (_Float16)acc[rr];
    // tiled store: [b][jblk=j0>>5][d=c][j0&31 .. +8)
    *(half8*)(hHT + (size_t)b * KTOT + (size_t)(j0 >> 5) * 4096 + c * 32 + (j0 & 31)) = hv;

    const float as = att_src[c], ad = att_dst[c];
#pragma unroll
    for (int rr = 0; rr < 8; ++rr) {
        float vs = acc[rr] * as, vd = acc[rr] * ad;
#pragma unroll
        for (int m = 16; m >= 1; m >>= 1) {
            vs += __shfl_xor(vs, m, 64);
            vd += __shfl_xor(vd, m, 64);
        }
        if ((t & 31) == 0) {
            srcA[(size_t)(b * HEADS + h) * NN + j0 + rr] = vs * LOG2E;
            dstA[(size_t)(b * HEADS + h) * NN + j0 + rr] = vd * LOG2E;
        }
    }
}

// ---------------- k_adjb: adj -> TRANSPOSED bitmask adjT[jw][i]; block 0 inits out -------
__global__ __launch_bounds__(256) void k_adjb(const int* __restrict__ adj,
                                              unsigned* __restrict__ adjT,
                                              const float* __restrict__ b_out,
                                              float* __restrict__ dout)
{
    const int t = threadIdx.x;
    if (blockIdx.x == 0 && t < 64) dout[t] = b_out[t & 15];
    const int gid = blockIdx.x * 256 + t;              // 0 .. N*N/8-1
    const int lane = t & 63;
    const int4* p = (const int4*)(adj + (size_t)gid * 8);
    const int4 a = p[0], b = p[1];
    unsigned byte =
        (a.x != 0 ? 1u : 0u)  | (a.y != 0 ? 2u : 0u)  | (a.z != 0 ? 4u : 0u)  | (a.w != 0 ? 8u : 0u) |
        (b.x != 0 ? 16u : 0u) | (b.y != 0 ? 32u : 0u) | (b.z != 0 ? 64u : 0u) | (b.w != 0 ? 128u : 0u);
    unsigned u = byte | (((unsigned)__shfl_xor((int)byte, 1, 64)) << 8);
    u = u | (((unsigned)__shfl_xor((int)u, 2, 64)) << 16);
    if ((lane & 3) == 0) {
        const int widx = gid >> 2;                     // = i*64 + jw
        const int i = widx >> 6, jw = widx & 63;
        adjT[(size_t)jw * NN + i] = u;                 // transposed
    }
}

// ---------------- k_attn: register flash-GAT, fully-coalesced fragment loads ------------
// grid 2048 x 256 thr; block = (iq 128, b 4, jq 4); 4 waves = 4 heads.
// hHT tiled => bb loads are contiguous-1KB wave loads; adjT => 64B word loads.
__global__ __launch_bounds__(256, 5) void k_attn(
    const unsigned* __restrict__ adjT, const _Float16* __restrict__ hHT,
    const float* __restrict__ srcA, const float* __restrict__ dstA,
    float* __restrict__ P, float* __restrict__ S)
{
    const int t = threadIdx.x;
    const int lane = t & 63;
    const int h = t >> 6;                // wave id = head
    const int bx = blockIdx.x;
    const int iq = bx & 127;
    const int b = (bx >> 7) & 3;
    const int jq = bx >> 9;
    const int i0 = iq * 16;
    const int jb0 = jq * 16;             // first 32-j block of this wave's 512-j slice

    const int r16 = lane & 15;
    const int g = lane >> 4;

    const float srci = srcA[(size_t)(b * HEADS + h) * NN + i0 + r16];
    const unsigned* adjr = adjT + (size_t)jb0 * NN + i0 + r16;                 // +n*NN
    const _Float16* hb = hHT + (size_t)b * KTOT + (size_t)jb0 * 4096
                             + (h * 32 + r16) * 32 + g * 8;                    // +n*4096
    const float4* dst4 = (const float4*)(dstA + (size_t)(b * HEADS + h) * NN + jq * 512) + 2 * g;

    f32x4 acc0 = {0.f, 0.f, 0.f, 0.f};
    f32x4 acc1 = {0.f, 0.f, 0.f, 0.f};
    f32x4 accS = {0.f, 0.f, 0.f, 0.f};
    const half8 ones = {(_Float16)1.f, (_Float16)1.f, (_Float16)1.f, (_Float16)1.f,
                        (_Float16)1.f, (_Float16)1.f, (_Float16)1.f, (_Float16)1.f};

#pragma unroll 1
    for (int n = 0; n < 16; ++n) {
        const unsigned word = adjr[(size_t)n * NN];          // 64B coalesced
        const half8 bb0 = *(const half8*)(hb + n * 4096);        // 1KB coalesced (d lo16)
        const half8 bb1 = *(const half8*)(hb + n * 4096 + 512);  // 1KB coalesced (d hi16)
        const float4 dv0 = dst4[n * 8];                          // broadcast
        const float4 dv1 = dst4[n * 8 + 1];

        const unsigned bits = word >> (8 * g);
        const float dvv[8] = {dv0.x, dv0.y, dv0.z, dv0.w, dv1.x, dv1.y, dv1.z, dv1.w};
        float wv[8];
#pragma unroll
        for (int e = 0; e < 8; ++e) {
            float s = srci + dvv[e];
            s = fmaxf(s, 0.2f * s);                                   // leaky relu (log2-scaled)
            const unsigned m = (unsigned)(((int)(bits << (31 - e))) >> 31);
            const unsigned su = __builtin_bit_cast(unsigned, s);
            wv[e] = __builtin_amdgcn_exp2f(
                __builtin_bit_cast(float, (su & m) | (NEGBIG_BITS & ~m)));
        }
        uint4v uu;
        uu[0] = __builtin_bit_cast(unsigned, __builtin_amdgcn_cvt_pkrtz(wv[0], wv[1]));
        uu[1] = __builtin_bit_cast(unsigned, __builtin_amdgcn_cvt_pkrtz(wv[2], wv[3]));
        uu[2] = __builtin_bit_cast(unsigned, __builtin_amdgcn_cvt_pkrtz(wv[4], wv[5]));
        uu[3] = __builtin_bit_cast(unsigned, __builtin_amdgcn_cvt_pkrtz(wv[6], wv[7]));
        const half8 af = __builtin_bit_cast(half8, uu);
        acc0 = __builtin_amdgcn_mfma_f32_16x16x32_f16(af, bb0, acc0, 0, 0, 0);
        acc1 = __builtin_amdgcn_mfma_f32_16x16x32_f16(af, bb1, acc1, 0, 0, 0);
        accS = __builtin_amdgcn_mfma_f32_16x16x32_f16(af, ones, accS, 0, 0, 0);
    }

    // direct store of this wave's disjoint output rows (verified layout: i=4g+r, d=r16)
    const size_t prow0 = (size_t)(jq * BB + b) * NN + i0;
#pragma unroll
    for (int r = 0; r < 4; ++r) {
        const size_t row = prow0 + 4 * g + r;
        P[row * HID + h * 32 + r16]      = acc0[r];
        P[row * HID + h * 32 + 16 + r16] = acc1[r];
        if (r16 == 0) S[row * HEADS + h] = accS[r];
    }
}

// ---------------- k_proj: combine 4 f32 partials + projection (W^T in LDS) --------------
__global__ __launch_bounds__(256) void k_proj(
    const float* __restrict__ P, const float* __restrict__ S,
    const float* __restrict__ W_out, float* __restrict__ dout)
{
    __shared__ float wlT[NQ][260];     // 16.6 KB
    __shared__ float red[256];

    const int t = threadIdx.x;
    const int k0 = blockIdx.x * 256;

#pragma unroll
    for (int u = 0; u < 4; ++u) {
        const int flat = (u * 256 + t) * 4;
        const float4 wv = *(const float4*)(W_out + (size_t)k0 * NQ + flat);
        const int krel = flat >> 4;
        const int q0 = flat & 15;
        wlT[q0 + 0][krel] = wv.x;
        wlT[q0 + 1][krel] = wv.y;
        wlT[q0 + 2][krel] = wv.z;
        wlT[q0 + 3][krel] = wv.w;
    }
    __syncthreads();

    const int q = t & 15;
    const int b = (t >> 4) & 3;
    const int ks = (t >> 6) * 64;
    const int i = (k0 + ks) >> 7;

    const float* p0 = P + (size_t)(0 * BB + b) * KTOT + k0 + ks;
    const float* p1 = P + (size_t)(1 * BB + b) * KTOT + k0 + ks;
    const float* p2 = P + (size_t)(2 * BB + b) * KTOT + k0 + ks;
    const float* p3 = P + (size_t)(3 * BB + b) * KTOT + k0 + ks;

    float acc = 0.f;
#pragma unroll
    for (int seg = 0; seg < 2; ++seg) {
        const int h = ((k0 + ks + seg * 32) >> 5) & 3;
        float rs = 0.f;
#pragma unroll
        for (int s = 0; s < NSL; ++s)
            rs += S[((size_t)(s * BB + b) * NN + i) * HEADS + h];
        const float inv = __builtin_amdgcn_rcpf(rs);
#pragma unroll
        for (int k4 = 0; k4 < 8; ++k4) {
            const int kk = seg * 32 + k4 * 4;
            const float4 a0 = *(const float4*)(p0 + kk);
            const float4 a1 = *(const float4*)(p1 + kk);
            const float4 a2 = *(const float4*)(p2 + kk);
            const float4 a3 = *(const float4*)(p3 + kk);
            const float4 wq = *(const float4*)&wlT[q][ks + kk];
            acc = fmaf(((a0.x + a1.x) + (a2.x + a3.x)) * inv, wq.x, acc);
            acc = fmaf(((a0.y + a1.y) + (a2.y + a3.y)) * inv, wq.y, acc);
            acc = fmaf(((a0.z + a1.z) + (a2.z + a3.z)) * inv, wq.z, acc);
            acc = fmaf(((a0.w + a1.w) + (a2.w + a3.w)) * inv, wq.w, acc);
        }
    }

    red[t] = acc;
    __syncthreads();
    if (t < 64)
        atomicAdd(&dout[t], red[t] + red[t + 64] + red[t + 128] + red[t + 192]);
}

extern "C" void kernel_launch(void* const* d_in, const int* in_sizes, int n_in,
                              void* d_out, int out_size, void* d_ws, size_t ws_size,
                              hipStream_t stream)
{
    const float* x       = (const float*)d_in[0];
    const int*   adj     = (const int*)d_in[1];
    const float* W_in    = (const float*)d_in[2];
    const float* b_in    = (const float*)d_in[3];
    const float* att_src = (const float*)d_in[4];
    const float* att_dst = (const float*)d_in[5];
    const float* W_out   = (const float*)d_in[6];
    const float* b_out   = (const float*)d_in[7];
    float* out = (float*)d_out;

    float* P    = (float*)d_ws;                              // NSL*BB*KTOT f32 = 16.8 MB
    float* S    = P + (size_t)NSL * BB * KTOT;               // 512 KB
    float* srcA = S + (size_t)NSL * BB * NN * HEADS;         // 128 KB
    float* dstA = srcA + (size_t)BB * HEADS * NN;            // 128 KB
    _Float16* hHT = (_Float16*)(dstA + (size_t)BB * HEADS * NN);          // 2 MB (tiled)
    unsigned* adjT = (unsigned*)((char*)hHT + sizeof(_Float16) * (size_t)BB * KTOT); // 512 KB

    k_hidden<<<BB * NN / 16, 256, 0, stream>>>(x, W_in, b_in, att_src, att_dst, hHT, srcA, dstA);
    k_adjb<<<NN * NN / 8 / 256, 256, 0, stream>>>(adj, adjT, b_out, out);
    k_attn<<<NSL * BB * (NN / 16), 256, 0, stream>>>(adjT, hHT, srcA, dstA, P, S);
    k_proj<<<KTOT / 256, 256, 0, stream>>>(P, S, W_out, out);
}

// Round 17
// 74.576 us; speedup vs baseline: 1.4181x; 1.0682x over previous
//
#include <hip/hip_runtime.h>
#include <math.h>

#define BB 4
#define NN 2048
#define CIN 64
#define HID 128
#define HEADS 4
#define NQ 16
#define KTOT (NN*HID) // 262144
#define LOG2E 1.44269504088896340736f
#define NEGBIG_BITS 0xC2C80000u   // -100.0f
#define NSL 4         // j-slices (512 j each)

typedef __attribute__((ext_vector_type(8))) _Float16 half8;
typedef __attribute__((ext_vector_type(4))) float f32x4;
typedef __attribute__((ext_vector_type(4))) unsigned uint4v;

// ---------------- k_hidden: h = x@W_in + b -> TILED hHT[b][jblk][d][j32], alphas ---------
__global__ __launch_bounds__(256) void k_hidden(
    const float* __restrict__ x, const float* __restrict__ W_in,
    const float* __restrict__ b_in, const float* __restrict__ att_src,
    const float* __restrict__ att_dst, _Float16* __restrict__ hHT,
    float* __restrict__ srcA, float* __restrict__ dstA)
{
    __shared__ float Wl[CIN * HID];   // 32 KB
    __shared__ float xl[16][CIN];     // 4 KB
    const int t = threadIdx.x;
    const int jj0 = blockIdx.x * 16;

    {
        const float4* Ws = (const float4*)W_in;
        float4* Wd = (float4*)Wl;
#pragma unroll
        for (int u = 0; u < 8; ++u) Wd[t + 256 * u] = Ws[t + 256 * u];
        ((float4*)&xl[0][0])[t] = ((const float4*)(x + (size_t)jj0 * CIN))[t];
    }
    __syncthreads();

    const int c = t & 127, rg = t >> 7;
    const int b = jj0 >> 11, j0 = (jj0 & (NN - 1)) + rg * 8;
    const int h = c >> 5;

    float acc[8];
    const float bc = b_in[c];
#pragma unroll
    for (int rr = 0; rr < 8; ++rr) acc[rr] = bc;

#pragma unroll
    for (int k4 = 0; k4 < CIN; k4 += 4) {
        const float w0 = Wl[(k4 + 0) * HID + c];
        const float w1 = Wl[(k4 + 1) * HID + c];
        const float w2 = Wl[(k4 + 2) * HID + c];
        const float w3 = Wl[(k4 + 3) * HID + c];
#pragma unroll
        for (int rr = 0; rr < 8; ++rr) {
            const float4 xv = *(const float4*)&xl[rg * 8 + rr][k4];
            acc[rr] = fmaf(xv.w, w3, fmaf(xv.z, w2, fmaf(xv.y, w1, fmaf(xv.x, w0, acc[rr]))));
        }
    }

    half8 hv;
#pragma unroll
    for (int rr = 0; rr < 8; ++rr) hv[rr] = (_Float16)acc[rr];
    // tiled store: [b][jblk=j0>>5][d=c][j0&31 .. +8)
    *(half8*)(hHT + (size_t)b * KTOT + (size_t)(j0 >> 5) * 4096 + c * 32 + (j0 & 31)) = hv;

    const float as = att_src[c], ad = att_dst[c];
#pragma unroll
    for (int rr = 0; rr < 8; ++rr) {
        float vs = acc[rr] * as, vd = acc[rr] * ad;
#pragma unroll
        for (int m = 16; m >= 1; m >>= 1) {
            vs += __shfl_xor(vs, m, 64);
            vd += __shfl_xor(vd, m, 64);
        }
        if ((t & 31) == 0) {
            srcA[(size_t)(b * HEADS + h) * NN + j0 + rr] = vs * LOG2E;
            dstA[(size_t)(b * HEADS + h) * NN + j0 + rr] = vd * LOG2E;
        }
    }
}

// ---------------- k_adjb: adj -> TRANSPOSED bitmask adjT[jw][i]; block 0 inits out -------
__global__ __launch_bounds__(256) void k_adjb(const int* __restrict__ adj,
                                              unsigned* __restrict__ adjT,
                                              const float* __restrict__ b_out,
                                              float* __restrict__ dout)
{
    const int t = threadIdx.x;
    if (blockIdx.x == 0 && t < 64) dout[t] = b_out[t & 15];
    const int gid = blockIdx.x * 256 + t;              // 0 .. N*N/8-1
    const int lane = t & 63;
    const int4* p = (const int4*)(adj + (size_t)gid * 8);
    const int4 a = p[0], b = p[1];
    unsigned byte =
        (a.x != 0 ? 1u : 0u)  | (a.y != 0 ? 2u : 0u)  | (a.z != 0 ? 4u : 0u)  | (a.w != 0 ? 8u : 0u) |
        (b.x != 0 ? 16u : 0u) | (b.y != 0 ? 32u : 0u) | (b.z != 0 ? 64u : 0u) | (b.w != 0 ? 128u : 0u);
    unsigned u = byte | (((unsigned)__shfl_xor((int)byte, 1, 64)) << 8);
    u = u | (((unsigned)__shfl_xor((int)u, 2, 64)) << 16);
    if ((lane & 3) == 0) {
        const int widx = gid >> 2;                     // = i*64 + jw
        const int i = widx >> 6, jw = widx & 63;
        adjT[(size_t)jw * NN + i] = u;                 // transposed
    }
}

// ---------------- k_attn: register flash-GAT, i-tile 32, coalesced loads ----------------
// grid 1024 x 256 thr; block = (iq 64, b 4, jq 4); 4 waves = 4 heads.
// Wave: 32 i-rows (2 A-frags) x 512 j; per iter 6 coalesced loads vs ~350 cyc compute.
__global__ __launch_bounds__(256, 4) void k_attn(
    const unsigned* __restrict__ adjT, const _Float16* __restrict__ hHT,
    const float* __restrict__ srcA, const float* __restrict__ dstA,
    float* __restrict__ P, float* __restrict__ S)
{
    const int t = threadIdx.x;
    const int lane = t & 63;
    const int h = t >> 6;                // wave id = head
    const int bx = blockIdx.x;
    const int iq = bx & 63;
    const int b = (bx >> 6) & 3;
    const int jq = bx >> 8;
    const int i0 = iq * 32;
    const int jb0 = jq * 16;             // first 32-j block of this wave's 512-j slice

    const int r16 = lane & 15;
    const int g = lane >> 4;

    const float srci0 = srcA[(size_t)(b * HEADS + h) * NN + i0 + r16];
    const float srci1 = srcA[(size_t)(b * HEADS + h) * NN + i0 + 16 + r16];
    const unsigned* adjr0 = adjT + (size_t)jb0 * NN + i0 + r16;                // +n*NN
    const unsigned* adjr1 = adjr0 + 16;
    const _Float16* hb = hHT + (size_t)b * KTOT + (size_t)jb0 * 4096
                             + (h * 32 + r16) * 32 + g * 8;                    // +n*4096
    const float4* dst4 = (const float4*)(dstA + (size_t)(b * HEADS + h) * NN + jq * 512) + 2 * g;

    f32x4 acc00 = {0.f, 0.f, 0.f, 0.f};   // frag0 (i0..i0+15), d lo16
    f32x4 acc01 = {0.f, 0.f, 0.f, 0.f};   // frag0, d hi16
    f32x4 acc10 = {0.f, 0.f, 0.f, 0.f};   // frag1 (i0+16..31), d lo16
    f32x4 acc11 = {0.f, 0.f, 0.f, 0.f};   // frag1, d hi16
    f32x4 accS0 = {0.f, 0.f, 0.f, 0.f};
    f32x4 accS1 = {0.f, 0.f, 0.f, 0.f};
    const half8 ones = {(_Float16)1.f, (_Float16)1.f, (_Float16)1.f, (_Float16)1.f,
                        (_Float16)1.f, (_Float16)1.f, (_Float16)1.f, (_Float16)1.f};

    // weights for one i-frag from adj bits + dst values (log2-scaled)
    auto MAKEAF = [&](float srci, unsigned bits, const float* dvv) -> half8 {
        float wv[8];
#pragma unroll
        for (int e = 0; e < 8; ++e) {
            float s = srci + dvv[e];
            s = fmaxf(s, 0.2f * s);                                   // leaky relu
            const unsigned m = (unsigned)(((int)(bits << (31 - e))) >> 31);
            const unsigned su = __builtin_bit_cast(unsigned, s);
            wv[e] = __builtin_amdgcn_exp2f(
                __builtin_bit_cast(float, (su & m) | (NEGBIG_BITS & ~m)));
        }
        uint4v uu;
        uu[0] = __builtin_bit_cast(unsigned, __builtin_amdgcn_cvt_pkrtz(wv[0], wv[1]));
        uu[1] = __builtin_bit_cast(unsigned, __builtin_amdgcn_cvt_pkrtz(wv[2], wv[3]));
        uu[2] = __builtin_bit_cast(unsigned, __builtin_amdgcn_cvt_pkrtz(wv[4], wv[5]));
        uu[3] = __builtin_bit_cast(unsigned, __builtin_amdgcn_cvt_pkrtz(wv[6], wv[7]));
        return __builtin_bit_cast(half8, uu);
    };

#pragma unroll 1
    for (int n = 0; n < 16; ++n) {
        const unsigned w0 = adjr0[(size_t)n * NN];           // 64B coalesced
        const unsigned w1 = adjr1[(size_t)n * NN];           // 64B coalesced
        const half8 bb0 = *(const half8*)(hb + n * 4096);        // 1KB coalesced (d lo16)
        const half8 bb1 = *(const half8*)(hb + n * 4096 + 512);  // 1KB coalesced (d hi16)
        const float4 dv0 = dst4[n * 8];                          // broadcast
        const float4 dv1 = dst4[n * 8 + 1];
        __builtin_amdgcn_sched_barrier(0);                   // keep load cluster intact

        const float dvv[8] = {dv0.x, dv0.y, dv0.z, dv0.w, dv1.x, dv1.y, dv1.z, dv1.w};
        const half8 af0 = MAKEAF(srci0, w0 >> (8 * g), dvv);
        const half8 af1 = MAKEAF(srci1, w1 >> (8 * g), dvv);
        acc00 = __builtin_amdgcn_mfma_f32_16x16x32_f16(af0, bb0, acc00, 0, 0, 0);
        acc01 = __builtin_amdgcn_mfma_f32_16x16x32_f16(af0, bb1, acc01, 0, 0, 0);
        accS0 = __builtin_amdgcn_mfma_f32_16x16x32_f16(af0, ones, accS0, 0, 0, 0);
        acc10 = __builtin_amdgcn_mfma_f32_16x16x32_f16(af1, bb0, acc10, 0, 0, 0);
        acc11 = __builtin_amdgcn_mfma_f32_16x16x32_f16(af1, bb1, acc11, 0, 0, 0);
        accS1 = __builtin_amdgcn_mfma_f32_16x16x32_f16(af1, ones, accS1, 0, 0, 0);
    }

    // direct store of both frags (verified layout: i = 4g+r, d = r16)
    const size_t prow0 = (size_t)(jq * BB + b) * NN + i0;
#pragma unroll
    for (int r = 0; r < 4; ++r) {
        const size_t row0 = prow0 + 4 * g + r;
        const size_t row1 = prow0 + 16 + 4 * g + r;
        P[row0 * HID + h * 32 + r16]      = acc00[r];
        P[row0 * HID + h * 32 + 16 + r16] = acc01[r];
        P[row1 * HID + h * 32 + r16]      = acc10[r];
        P[row1 * HID + h * 32 + 16 + r16] = acc11[r];
        if (r16 == 0) {
            S[row0 * HEADS + h] = accS0[r];
            S[row1 * HEADS + h] = accS1[r];
        }
    }
}

// ---------------- k_proj: combine 4 f32 partials + projection (W^T in LDS) --------------
__global__ __launch_bounds__(256) void k_proj(
    const float* __restrict__ P, const float* __restrict__ S,
    const float* __restrict__ W_out, float* __restrict__ dout)
{
    __shared__ float wlT[NQ][260];     // 16.6 KB
    __shared__ float red[256];

    const int t = threadIdx.x;
    const int k0 = blockIdx.x * 256;

#pragma unroll
    for (int u = 0; u < 4; ++u) {
        const int flat = (u * 256 + t) * 4;
        const float4 wv = *(const float4*)(W_out + (size_t)k0 * NQ + flat);
        const int krel = flat >> 4;
        const int q0 = flat & 15;
        wlT[q0 + 0][krel] = wv.x;
        wlT[q0 + 1][krel] = wv.y;
        wlT[q0 + 2][krel] = wv.z;
        wlT[q0 + 3][krel] = wv.w;
    }
    __syncthreads();

    const int q = t & 15;
    const int b = (t >> 4) & 3;
    const int ks = (t >> 6) * 64;
    const int i = (k0 + ks) >> 7;

    const float* p0 = P + (size_t)(0 * BB + b) * KTOT + k0 + ks;
    const float* p1 = P + (size_t)(1 * BB + b) * KTOT + k0 + ks;
    const float* p2 = P + (size_t)(2 * BB + b) * KTOT + k0 + ks;
    const float* p3 = P + (size_t)(3 * BB + b) * KTOT + k0 + ks;

    float acc = 0.f;
#pragma unroll
    for (int seg = 0; seg < 2; ++seg) {
        const int h = ((k0 + ks + seg * 32) >> 5) & 3;
        float rs = 0.f;
#pragma unroll
        for (int s = 0; s < NSL; ++s)
            rs += S[((size_t)(s * BB + b) * NN + i) * HEADS + h];
        const float inv = __builtin_amdgcn_rcpf(rs);
#pragma unroll
        for (int k4 = 0; k4 < 8; ++k4) {
            const int kk = seg * 32 + k4 * 4;
            const float4 a0 = *(const float4*)(p0 + kk);
            const float4 a1 = *(const float4*)(p1 + kk);
            const float4 a2 = *(const float4*)(p2 + kk);
            const float4 a3 = *(const float4*)(p3 + kk);
            const float4 wq = *(const float4*)&wlT[q][ks + kk];
            acc = fmaf(((a0.x + a1.x) + (a2.x + a3.x)) * inv, wq.x, acc);
            acc = fmaf(((a0.y + a1.y) + (a2.y + a3.y)) * inv, wq.y, acc);
            acc = fmaf(((a0.z + a1.z) + (a2.z + a3.z)) * inv, wq.z, acc);
            acc = fmaf(((a0.w + a1.w) + (a2.w + a3.w)) * inv, wq.w, acc);
        }
    }

    red[t] = acc;
    __syncthreads();
    if (t < 64)
        atomicAdd(&dout[t], red[t] + red[t + 64] + red[t + 128] + red[t + 192]);
}

extern "C" void kernel_launch(void* const* d_in, const int* in_sizes, int n_in,
                              void* d_out, int out_size, void* d_ws, size_t ws_size,
                              hipStream_t stream)
{
    const float* x       = (const float*)d_in[0];
    const int*   adj     = (const int*)d_in[1];
    const float* W_in    = (const float*)d_in[2];
    const float* b_in    = (const float*)d_in[3];
    const float* att_src = (const float*)d_in[4];
    const float* att_dst = (const float*)d_in[5];
    const float* W_out   = (const float*)d_in[6];
    const float* b_out   = (const float*)d_in[7];
    float* out = (float*)d_out;

    float* P    = (float*)d_ws;                              // NSL*BB*KTOT f32 = 16.8 MB
    float* S    = P + (size_t)NSL * BB * KTOT;               // 512 KB
    float* srcA = S + (size_t)NSL * BB * NN * HEADS;         // 128 KB
    float* dstA = srcA + (size_t)BB * HEADS * NN;            // 128 KB
    _Float16* hHT = (_Float16*)(dstA + (size_t)BB * HEADS * NN);          // 2 MB (tiled)
    unsigned* adjT = (unsigned*)((char*)hHT + sizeof(_Float16) * (size_t)BB * KTOT); // 512 KB

    k_hidden<<<BB * NN / 16, 256, 0, stream>>>(x, W_in, b_in, att_src, att_dst, hHT, srcA, dstA);
    k_adjb<<<NN * NN / 8 / 256, 256, 0, stream>>>(adj, adjT, b_out, out);
    // block = (iq 64, b 4, jq 4) -> 1024 blocks x 4 waves
    k_attn<<<NSL * BB * (NN / 32), 256, 0, stream>>>(adjT, hHT, srcA, dstA, P, S);
    k_proj<<<KTOT / 256, 256, 0, stream>>>(P, S, W_out, out);
}